// Round 14
// baseline (245.835 us; speedup 1.0000x reference)
//
#include <hip/hip_runtime.h>
#include <stdint.h>

typedef unsigned short u16;
typedef unsigned int   u32;
typedef unsigned long long u64;

#define F_DIM 256
#define O_DIM 24
#define MARGIN  3.0f      // capture margin (>= 2E bf16-vs-fp32 score bound; validated R2-R13)
#define FMARGIN 3.0f      // rescore global filter margin (same bound)
#define WCAP 512          // candidate slots per capture-wave (8 B each)
#define NWAVE_CAP 5120    // 16 mb * 80 chunks * 4 waves

#define AS1 __attribute__((address_space(1)))
#define AS3 __attribute__((address_space(3)))

typedef __bf16 bf16x8 __attribute__((ext_vector_type(8)));
typedef float  f32x4  __attribute__((ext_vector_type(4)));

__device__ __forceinline__ u32 ordf(float s) {
    u32 b = __float_as_uint(s);
    return (b & 0x80000000u) ? ~b : (b | 0x80000000u);
}
__device__ __forceinline__ float iordf(u32 e) {   // inverse of ordf
    return __uint_as_float((e & 0x80000000u) ? (e ^ 0x80000000u) : ~e);
}
__device__ __forceinline__ u16 f2bf(float f) {   // round-to-nearest-even
    u32 u = __float_as_uint(f);
    u32 r = (u + 0x7FFFu + ((u >> 16) & 1u)) >> 16;
    return (u16)r;
}

// ---------------- init (fallback path only) ----------------
__global__ void init_kernel(u64* best, u32* gminu, int B) {
    int i = blockIdx.x * blockDim.x + threadIdx.x;
    if (i < B) { best[i] = ~0ull; if (gminu) gminu[i] = ordf(1e30f); }
}

// ---------------- t2 (fallback path only) ----------------
__global__ void t2_kernel(const float* __restrict__ X, float* __restrict__ t2,
                          int N, int Npad) {
    int tid = threadIdx.x;
    int row = blockIdx.x * 4 + (tid >> 6);
    int lane = tid & 63;
    if (row >= Npad) return;
    if (row >= N) { if (lane == 0) t2[row] = 1e30f; return; }
    float4 v = ((const float4*)(X + (size_t)row * F_DIM))[lane];
    float s = v.x * v.x + v.y * v.y + v.z * v.z + v.w * v.w;
    #pragma unroll
    for (int off = 32; off > 0; off >>= 1) s += __shfl_down(s, off, 64);
    if (lane == 0) t2[row] = s;
}

// ---------------- merged converter: x-tiles and Xt-tiles in ONE launch ----------------
// blockIdx.x < mt128 -> x (fused best/gminu init); else Xt (fused t2).
__global__ __launch_bounds__(256) void convert_dual(
        const float* __restrict__ x, u16* __restrict__ xbf, int B,
        const float* __restrict__ Xt, u16* __restrict__ xtbf, float* __restrict__ t2out, int N,
        int mt128, u64* best, u32* gminu) {
    __shared__ u16 tl[8192];   // 16 KB
    const int tid = threadIdx.x;
    const int tg = blockIdx.x, p = blockIdx.y;
    const bool isX = tg < mt128;
    const int t = isX ? tg : tg - mt128;
    const float* src = isX ? x : Xt;
    u16* dst = isX ? xbf : xtbf;
    const int nrows = isX ? B : N;
    if (isX) {
        int id = (p * mt128 + t) * 256 + tid;
        if (id < B) { best[id] = ~0ull; gminu[id] = ordf(1e30f); }
    }
    const int w = tid >> 6, L = tid & 63;
    const int col = L * 4;
    const int ks = col >> 5, j = col & 7, lhi = ((col >> 3) & 3) << 4;
    #pragma unroll
    for (int i = 0; i < 8; ++i) {
        int rloc = i * 4 + w;
        int grow = t * 128 + p * 32 + rloc;
        float4 v = make_float4(0.f, 0.f, 0.f, 0.f);
        if (grow < nrows) v = *(const float4*)(src + (size_t)grow * F_DIM + col);
        if (!isX) {
            float s = v.x * v.x + v.y * v.y + v.z * v.z + v.w * v.w;
            #pragma unroll
            for (int off = 32; off > 0; off >>= 1) s += __shfl_down(s, off, 64);
            if (L == 0) t2out[grow] = (grow < nrows) ? s : 1e30f;
        }
        u16* q = &tl[ks * 1024 + (rloc >> 4) * 512 + (((rloc & 15) | lhi)) * 8 + j];
        q[0] = f2bf(v.x); q[1] = f2bf(v.y); q[2] = f2bf(v.z); q[3] = f2bf(v.w);
    }
    __syncthreads();
    const uint4* s4 = (const uint4*)tl;
    uint4* d4 = (uint4*)(dst + (size_t)t * 32768);
    #pragma unroll
    for (int v = 0; v < 4; ++v) {
        int lin = v * 256 + tid;
        int ksc = lin >> 7, subl = (lin >> 6) & 1, lane = lin & 63;
        d4[(ksc * 8 + 2 * p + subl) * 64 + lane] = s4[lin];
    }
}

// ---------------- main: R14 = R13 block (4-wave, 32 KB, 88 reg) at 5 blocks/CU ----------------
// R13 refuted the phase-lock theory (4 independent blocks/CU, same ~11K cyc/tile floor).
// Invariant across ALL variants: ~4 waves/SIMD and a 1.5-2K-cycle dependent chain per
// iteration (ds_read 120 + 8-deep MFMA chains + 5-6-stage shfl butterflies/scans at
// ~35% issue density) -> 4 waves cover ~8K of the 11K window = the measured ~65% idle.
// Floor = chain latency x insufficient TLP. R14 raises TLP 25% at constant block
// design: R13's block needs 32 KB LDS + 88 regs, so FIVE fit per CU (LDS 5x32=160
// exact; regs 20x88=1760<=2048) -- the R13 grid (1024) only supplied 4/CU. NCH=80 ->
// 16 mb x 80 chunks = 1280 blocks = exactly 5/CU -> 20 waves/CU, 5 waves/SIMD.
// Swizzle: 10 chunks/XCD (per-XCD set: B 3.2 MB + A 1 MB ~ L2, unchanged).
__global__ __launch_bounds__(256, 2) void knn_mfma(
    const u16* __restrict__ xbf, const u16* __restrict__ xtbf,
    const float* __restrict__ t2, u32* __restrict__ gminu,
    u32* __restrict__ wavecnt, u64* __restrict__ cands,
    int ntiles /*32-col tiles*/, int nch)
{
    __shared__ u16 sB[2][8192];   // 2 x 16 KB (32-col half-tiles)

    const int tid = threadIdx.x;
    const int L = tid & 63, w = tid >> 6;   // 4 waves
    const int lid = blockIdx.x;
    const int mbcnt = (int)(gridDim.x) / nch;
    int mb, chunk;
    if (mbcnt == 16 && (nch & 7) == 0) {
        const int cpx = nch >> 3;                  // chunks per XCD (80 -> 10)
        const int xg = lid & 7, slot = lid >> 3;   // slot in [0, 16*cpx)
        chunk = xg * cpx + (slot >> 4);
        mb = slot & 15;                            // all 16 mb per XCD
    } else {
        mb = lid % mbcnt;                          // legacy linearization
        chunk = lid / mbcnt;
    }
    const int gwave = (mb * nch + chunk) * 4 + w;
    const int t0 = (int)(((long long)chunk * ntiles) / nch);
    const int t1 = (int)(((long long)(chunk + 1) * ntiles) / nch);

    // nt is a 32-col half-tile: nt64 = nt>>1, half = nt&1
    #define TBASE_U32(nt) ((const AS1 u32*)xtbf + (size_t)((nt) >> 2) * 16384 \
                           + (size_t)(((nt) >> 1) & 1) * 1024 + (size_t)((nt) & 1) * 512)

    // ---- stage one 16 KB half-tile (async, 4 rounds x 256 threads x 16 B) ----
    #define STAGE(buf, nt) do {                                                        \
        const AS1 u32* gp_ = TBASE_U32(nt);                                            \
        AS3 u32* lb_ = (AS3 u32*)&sB[buf][0];                                          \
        _Pragma("unroll")                                                              \
        for (int j = 0; j < 4; ++j) {                                                  \
            const int unit = j * 4 + w;                                                \
            __builtin_amdgcn_global_load_lds(                                          \
                gp_ + (size_t)(unit >> 1) * 2048 + (size_t)(unit & 1) * 256            \
                    + (size_t)L * 4,                                                   \
                lb_ + unit * 256, 16, 0, 0);                                           \
        }                                                                              \
    } while (0)

    STAGE(0, t0);

    // ---- A fragments in registers: wave w owns rows mb*128 + w*32 .. +31 ----
    bf16x8 areg[16];
    {
        const u16* base = xbf + (size_t)mb * 32768 + (size_t)w * 1024 + (size_t)L * 8;
        #pragma unroll
        for (int ks = 0; ks < 8; ++ks)
            #pragma unroll
            for (int i = 0; i < 2; ++i)
                areg[ks * 2 + i] = *(const bf16x8*)(base + ks * 4096 + i * 512);
    }

    float rowmin_reg[2][4];
    #pragma unroll
    for (int i = 0; i < 2; ++i)
        #pragma unroll
        for (int r = 0; r < 4; ++r) rowmin_reg[i][r] = 1e30f;

    u32 wcount = 0;
    u64* const wreg = cands + (size_t)gwave * WCAP;

    __syncthreads();   // first half-tile staged

    for (int nt = t0; nt < t1; ++nt) {
        const int cur = (nt - t0) & 1;

        // t2 loads FIRST (R9): their wait must not drain the fresh prefetch
        float t2v[2];
        #pragma unroll
        for (int c = 0; c < 2; ++c) t2v[c] = t2[nt * 32 + (L & 15) + c * 16];

        if (nt + 1 < t1) STAGE(cur ^ 1, nt + 1);   // prefetch into other buffer

        f32x4 acc[2][2];
        #pragma unroll
        for (int i = 0; i < 2; ++i)
            #pragma unroll
            for (int c = 0; c < 2; ++c)
                #pragma unroll
                for (int r = 0; r < 4; ++r) acc[i][c][r] = 0.f;

        #pragma unroll
        for (int ks = 0; ks < 8; ++ks) {
            bf16x8 bc[2];
            #pragma unroll
            for (int c = 0; c < 2; ++c)
                bc[c] = *(const bf16x8*)&sB[cur][ks * 1024 + c * 512 + L * 8];
            #pragma unroll
            for (int i = 0; i < 2; ++i)
                #pragma unroll
                for (int c = 0; c < 2; ++c)
                    acc[i][c] = __builtin_amdgcn_mfma_f32_16x16x32_bf16(areg[ks * 2 + i], bc[c], acc[i][c], 0, 0, 0);
        }

        // ---- epilogue ----
        const int colb = nt * 32 + (L & 15);
        float r4[2][4];
        #pragma unroll
        for (int i = 0; i < 2; ++i) {
            #pragma unroll
            for (int r = 0; r < 4; ++r) r4[i][r] = 1e30f;
            #pragma unroll
            for (int c = 0; c < 2; ++c)
                #pragma unroll
                for (int r = 0; r < 4; ++r)
                    r4[i][r] = fminf(r4[i][r], fmaf(-2.f, acc[i][c][r], t2v[c]));
        }

        // threshold base (subset-min of the row's bf16 scores: safe with MARGIN >= 2E)
        float thb[2][4];
        if (nt == t0) {
            // seed: butterfly tile-t0 row-min FIRST so t0 capture doesn't flood
            #pragma unroll
            for (int i = 0; i < 2; ++i)
                #pragma unroll
                for (int r = 0; r < 4; ++r) rowmin_reg[i][r] = r4[i][r];
            #pragma unroll
            for (int st = 1; st <= 8; st <<= 1)
                #pragma unroll
                for (int i = 0; i < 2; ++i)
                    #pragma unroll
                    for (int r = 0; r < 4; ++r)
                        rowmin_reg[i][r] = fminf(rowmin_reg[i][r], __shfl_xor(rowmin_reg[i][r], st, 64));
            #pragma unroll
            for (int i = 0; i < 2; ++i)
                #pragma unroll
                for (int r = 0; r < 4; ++r) thb[i][r] = rowmin_reg[i][r];
        } else {
            #pragma unroll
            for (int i = 0; i < 2; ++i)
                #pragma unroll
                for (int r = 0; r < 4; ++r) thb[i][r] = fminf(rowmin_reg[i][r], r4[i][r]);
        }

        bool anyhit = false;
        #pragma unroll
        for (int i = 0; i < 2; ++i)
            #pragma unroll
            for (int r = 0; r < 4; ++r)
                anyhit = anyhit || (r4[i][r] < thb[i][r] + MARGIN);

        if (__any(anyhit)) {
            u32 cnt = 0;
            #pragma unroll
            for (int i = 0; i < 2; ++i)
                #pragma unroll
                for (int r = 0; r < 4; ++r) {
                    float th = thb[i][r] + MARGIN;
                    if (r4[i][r] < th) {
                        #pragma unroll
                        for (int c = 0; c < 2; ++c)
                            cnt += (fmaf(-2.f, acc[i][c][r], t2v[c]) < th) ? 1u : 0u;
                    }
                }
            u32 pre = cnt;
            #pragma unroll
            for (int d = 1; d < 64; d <<= 1) {
                u32 v = __shfl_up(pre, d, 64);
                if (L >= d) pre += v;
            }
            u32 total = __shfl(pre, 63, 64);
            u32 woff = wcount + pre - cnt;
            #pragma unroll
            for (int i = 0; i < 2; ++i)
                #pragma unroll
                for (int r = 0; r < 4; ++r) {
                    float th = thb[i][r] + MARGIN;
                    if (r4[i][r] < th) {
                        const int q = mb * 128 + w * 32 + i * 16 + (L >> 4) * 4 + r;
                        #pragma unroll
                        for (int c = 0; c < 2; ++c) {
                            float s = fmaf(-2.f, acc[i][c][r], t2v[c]);
                            if (s < th) {
                                if (woff < WCAP)
                                    wreg[woff] = ((u64)__float_as_uint(s) << 32)
                                               | (u64)(((u32)q << 16) | (u32)(colb + c * 16));
                                woff++;
                            }
                        }
                    }
                }
            wcount += total;
        }

        // fold per-lane; full 16-lane butterfly only every 4th tile
        #pragma unroll
        for (int i = 0; i < 2; ++i)
            #pragma unroll
            for (int r = 0; r < 4; ++r)
                rowmin_reg[i][r] = fminf(rowmin_reg[i][r], r4[i][r]);
        if (((nt - t0) & 3) == 3) {
            #pragma unroll
            for (int st = 1; st <= 8; st <<= 1)
                #pragma unroll
                for (int i = 0; i < 2; ++i)
                    #pragma unroll
                    for (int r = 0; r < 4; ++r)
                        rowmin_reg[i][r] = fminf(rowmin_reg[i][r], __shfl_xor(rowmin_reg[i][r], st, 64));
        }

        __syncthreads();   // drains next-tile stage + protects buffer reuse (4-wave barrier)
    }

    // ---- final: exact chunk row-min -> global gmin atomics + candidate count ----
    #pragma unroll
    for (int st = 1; st <= 8; st <<= 1)
        #pragma unroll
        for (int i = 0; i < 2; ++i)
            #pragma unroll
            for (int r = 0; r < 4; ++r)
                rowmin_reg[i][r] = fminf(rowmin_reg[i][r], __shfl_xor(rowmin_reg[i][r], st, 64));
    if ((L & 15) == 0) {
        #pragma unroll
        for (int i = 0; i < 2; ++i)
            #pragma unroll
            for (int r = 0; r < 4; ++r) {
                int q = mb * 128 + w * 32 + i * 16 + (L >> 4) * 4 + r;
                atomicMin(&gminu[q], ordf(rowmin_reg[i][r]));
            }
    }
    if (L == 0) wavecnt[gwave] = (wcount < WCAP) ? wcount : WCAP;
    #undef STAGE
    #undef TBASE_U32
}

// ---------------- filtered exact fp32 rescore: ballot-compacted, wave-cooperative ----------------
__global__ void rescore(const float* __restrict__ x, const float* __restrict__ Xt,
                        const float* __restrict__ t2, const u32* __restrict__ gminu,
                        const u32* __restrict__ wavecnt, const u64* __restrict__ cands,
                        u64* __restrict__ best) {
    const int L = threadIdx.x & 63;
    const int gw = blockIdx.x * (blockDim.x >> 6) + (threadIdx.x >> 6);
    if (gw >= NWAVE_CAP) return;
    u32 cnt = wavecnt[gw];
    if (cnt > WCAP) cnt = WCAP;
    const u64* reg = cands + (size_t)gw * WCAP;
    for (u32 base = 0; base < cnt; base += 64) {
        u32 i = base + L;
        u64 rec = 0; bool pass = false;
        if (i < cnt) {
            rec = reg[i];                                   // coalesced 512 B
            float sb = __uint_as_float((u32)(rec >> 32));
            int q = (int)((rec >> 16) & 0xFFFFu);
            pass = sb < iordf(gminu[q]) + FMARGIN;
        }
        u64 bal = __ballot(pass);
        while (bal) {
            int j = __ffsll((unsigned long long)bal) - 1;
            bal &= bal - 1;
            u64 r2 = __shfl(rec, j, 64);
            int q = (int)((r2 >> 16) & 0xFFFFu);
            int n = (int)(r2 & 0xFFFFu);
            float4 a = *((const float4*)(x  + (size_t)q * F_DIM) + L);
            float4 b = *((const float4*)(Xt + (size_t)n * F_DIM) + L);
            float d = fmaf(a.x, b.x, fmaf(a.y, b.y, fmaf(a.z, b.z, a.w * b.w)));
            #pragma unroll
            for (int st = 32; st > 0; st >>= 1) d += __shfl_xor(d, st, 64);
            if (L == 0) {
                float s = fmaf(-2.f, d, t2[n]);
                u64 p = ((u64)ordf(s) << 32) | (u32)n;
                atomicMin(&best[q], p);
            }
        }
    }
}

// ---------------- gather Y[nearest] ----------------
__global__ void gather_kernel(const float* __restrict__ Y, const u64* __restrict__ best,
                              float* __restrict__ out, int B, int N) {
    int gid = blockIdx.x * blockDim.x + threadIdx.x;
    int total = B * O_DIM;
    if (gid >= total) return;
    int b = gid / O_DIM;
    int o = gid - b * O_DIM;
    u32 n = (u32)(best[b] & 0xFFFFFFFFull);
    if (n >= (u32)N) n = 0;   // defensive
    out[gid] = Y[(size_t)n * O_DIM + o];
}

// ================= fp32 fallback (proven Round-1 path, used if ws too small) =================
#define BM 128
#define BN 128
#define BK 16
#define NSPLIT 64
#define LDA (BM + 4)

__global__ __launch_bounds__(256) void knn_main_fp32(
    const float* __restrict__ Xq, const float* __restrict__ Xt,
    const float* __restrict__ t2, u64* __restrict__ best, int N)
{
    __shared__ float As[BK][LDA];
    __shared__ float Bs[BK][LDA];
    __shared__ u64 red[BM][17];

    const int tid = threadIdx.x;
    const int tx = tid & 15;
    const int ty = tid >> 4;
    const int m0 = blockIdx.y * BM;
    const int CHUNK = (N + NSPLIT - 1) / NSPLIT;
    const int n0c = blockIdx.x * CHUNK;
    const int n1c = min(N, n0c + CHUNK);

    u64 bestv[8];
    #pragma unroll
    for (int i = 0; i < 8; ++i) bestv[i] = ~0ull;

    const int srow = tid >> 2;
    const int scol4 = (tid & 3) * 4;

    for (int nt = n0c; nt < n1c; nt += BN) {
        float accl[8][8];
        #pragma unroll
        for (int i = 0; i < 8; ++i)
            #pragma unroll
            for (int j = 0; j < 8; ++j) accl[i][j] = 0.f;
        for (int k0 = 0; k0 < F_DIM; k0 += BK) {
            #pragma unroll
            for (int h = 0; h < 2; ++h) {
                int row = h * 64 + srow;
                float4 av = *(const float4*)(Xq + (size_t)(m0 + row) * F_DIM + k0 + scol4);
                As[scol4 + 0][row] = av.x; As[scol4 + 1][row] = av.y;
                As[scol4 + 2][row] = av.z; As[scol4 + 3][row] = av.w;
                int n = nt + row;
                float4 bv = make_float4(0.f, 0.f, 0.f, 0.f);
                if (n < n1c) bv = *(const float4*)(Xt + (size_t)n * F_DIM + k0 + scol4);
                Bs[scol4 + 0][row] = bv.x; Bs[scol4 + 1][row] = bv.y;
                Bs[scol4 + 2][row] = bv.z; Bs[scol4 + 3][row] = bv.w;
            }
            __syncthreads();
            #pragma unroll
            for (int k = 0; k < BK; ++k) {
                float4 a0 = *(const float4*)&As[k][ty * 4];
                float4 a1 = *(const float4*)&As[k][64 + ty * 4];
                float4 b0 = *(const float4*)&Bs[k][tx * 4];
                float4 b1 = *(const float4*)&Bs[k][64 + tx * 4];
                float am[8] = {a0.x, a0.y, a0.z, a0.w, a1.x, a1.y, a1.z, a1.w};
                float bn[8] = {b0.x, b0.y, b0.z, b0.w, b1.x, b1.y, b1.z, b1.w};
                #pragma unroll
                for (int i = 0; i < 8; ++i)
                    #pragma unroll
                    for (int j = 0; j < 8; ++j)
                        accl[i][j] = fmaf(am[i], bn[j], accl[i][j]);
            }
            __syncthreads();
        }
        #pragma unroll
        for (int j = 0; j < 8; ++j) {
            int nl = (j < 4) ? (tx * 4 + j) : (64 + tx * 4 + (j - 4));
            int n = nt + nl;
            if (n < n1c) {
                float t2v = t2[n];
                #pragma unroll
                for (int i = 0; i < 8; ++i) {
                    float score = fmaf(-2.f, accl[i][j], t2v);
                    u64 p = ((u64)ordf(score) << 32) | (u32)n;
                    bestv[i] = (p < bestv[i]) ? p : bestv[i];
                }
            }
        }
    }
    #pragma unroll
    for (int i = 0; i < 8; ++i) {
        int ml = (i < 4) ? (ty * 4 + i) : (64 + ty * 4 + (i - 4));
        red[ml][tx] = bestv[i];
    }
    __syncthreads();
    if (tid < BM) {
        u64 b = red[tid][0];
        #pragma unroll
        for (int t = 1; t < 16; ++t) { u64 v = red[tid][t]; b = (v < b) ? v : b; }
        atomicMin(&best[m0 + tid], b);
    }
}

// ================= launch =================
extern "C" void kernel_launch(void* const* d_in, const int* in_sizes, int n_in,
                              void* d_out, int out_size, void* d_ws, size_t ws_size,
                              hipStream_t stream) {
    const float* x  = (const float*)d_in[0];
    const float* Xt = (const float*)d_in[1];
    const float* Yt = (const float*)d_in[2];
    float* out = (float*)d_out;

    const int B = in_sizes[0] / F_DIM;        // 2048
    const int N = in_sizes[1] / F_DIM;        // 50000
    const int NT128 = (N + 127) / 128;        // 391
    const int Npad = NT128 * 128;             // 50048
    const int NT64 = NT128 * 2;               // 782
    const int NT32 = NT64 * 2;                // 1564
    const int MB = B / 128;                   // 16 (128-row m-blocks)
    const int MT128 = B / 128;                // 16
    const int NCH = 80;                       // 16*80 = 1280 blocks = 5/CU (256 thr each)

    char* wsp = (char*)d_ws;
    size_t off = 0;
    auto nxt = [&](size_t bytes) {
        char* p = wsp + off;
        off = (off + bytes + 255) & ~(size_t)255;
        return p;
    };
    float* t2       = (float*)nxt((size_t)Npad * 4);
    u64*   best     = (u64*)  nxt((size_t)B * 8);
    u32*   wavecnt  = (u32*)  nxt((size_t)NWAVE_CAP * 4);
    u32*   gminu    = (u32*)  nxt((size_t)B * 4);
    u64*   cands    = (u64*)  nxt((size_t)NWAVE_CAP * WCAP * 8);
    u16*   xbf      = (u16*)  nxt((size_t)B * F_DIM * 2);
    u16*   xtbf     = (u16*)  nxt((size_t)Npad * F_DIM * 2);
    size_t required = off;

    if (ws_size >= required && B % 128 == 0 && MB * NCH * 4 <= NWAVE_CAP) {
        // 4 launches: convert_dual(x+Xt, fused init+t2), knn_mfma(+gmin atomics), rescore, gather
        convert_dual<<<dim3(MT128 + NT128, 4), 256, 0, stream>>>(
            x, xbf, B, Xt, xtbf, t2, N, MT128, best, gminu);
        knn_mfma<<<dim3(MB * NCH), 256, 0, stream>>>(xbf, xtbf, t2, gminu, wavecnt, cands, NT32, NCH);
        rescore<<<(NWAVE_CAP + 3) / 4, 256, 0, stream>>>(x, Xt, t2, gminu, wavecnt, cands, best);
    } else {
        init_kernel<<<(B + 255) / 256, 256, 0, stream>>>(best, (u32*)nullptr, B);
        t2_kernel<<<(N + 3) / 4, 256, 0, stream>>>(Xt, t2, N, N);
        dim3 grid(NSPLIT, B / BM);
        knn_main_fp32<<<grid, 256, 0, stream>>>(x, Xt, t2, best, N);
    }

    int total = B * O_DIM;
    gather_kernel<<<(total + 255) / 256, 256, 0, stream>>>(Yt, best, out, B, N);
}

// Round 15
// 213.106 us; speedup vs baseline: 1.1536x; 1.1536x over previous
//
#include <hip/hip_runtime.h>
#include <stdint.h>

typedef unsigned short u16;
typedef unsigned int   u32;
typedef unsigned long long u64;

#define F_DIM 256
#define O_DIM 24
#define MARGIN  3.0f      // capture margin (>= 2E bf16-vs-fp32 score bound; validated R2-R13)
#define FMARGIN 3.0f      // rescore global filter margin (same bound)
#define WCAP 512          // candidate slots per capture-wave (8 B each)
#define NWAVE_CAP 4096    // 8 mb * 64 chunks * 8 waves

#define AS1 __attribute__((address_space(1)))
#define AS3 __attribute__((address_space(3)))

typedef __bf16 bf16x8 __attribute__((ext_vector_type(8)));
typedef float  f32x4  __attribute__((ext_vector_type(4)));

__device__ __forceinline__ u32 ordf(float s) {
    u32 b = __float_as_uint(s);
    return (b & 0x80000000u) ? ~b : (b | 0x80000000u);
}
__device__ __forceinline__ float iordf(u32 e) {   // inverse of ordf
    return __uint_as_float((e & 0x80000000u) ? (e ^ 0x80000000u) : ~e);
}
__device__ __forceinline__ u16 f2bf(float f) {   // round-to-nearest-even
    u32 u = __float_as_uint(f);
    u32 r = (u + 0x7FFFu + ((u >> 16) & 1u)) >> 16;
    return (u16)r;
}

// ---------------- init (fallback path only) ----------------
__global__ void init_kernel(u64* best, u32* gminu, int B) {
    int i = blockIdx.x * blockDim.x + threadIdx.x;
    if (i < B) { best[i] = ~0ull; if (gminu) gminu[i] = ordf(1e30f); }
}

// ---------------- t2 (fallback path only) ----------------
__global__ void t2_kernel(const float* __restrict__ X, float* __restrict__ t2,
                          int N, int Npad) {
    int tid = threadIdx.x;
    int row = blockIdx.x * 4 + (tid >> 6);
    int lane = tid & 63;
    if (row >= Npad) return;
    if (row >= N) { if (lane == 0) t2[row] = 1e30f; return; }
    float4 v = ((const float4*)(X + (size_t)row * F_DIM))[lane];
    float s = v.x * v.x + v.y * v.y + v.z * v.z + v.w * v.w;
    #pragma unroll
    for (int off = 32; off > 0; off >>= 1) s += __shfl_down(s, off, 64);
    if (lane == 0) t2[row] = s;
}

// ---------------- merged converter: x-tiles and Xt-tiles in ONE launch ----------------
// blockIdx.x < mt128 -> x (fused best/gminu init); else Xt (fused t2).
__global__ __launch_bounds__(256) void convert_dual(
        const float* __restrict__ x, u16* __restrict__ xbf, int B,
        const float* __restrict__ Xt, u16* __restrict__ xtbf, float* __restrict__ t2out, int N,
        int mt128, u64* best, u32* gminu) {
    __shared__ u16 tl[8192];   // 16 KB
    const int tid = threadIdx.x;
    const int tg = blockIdx.x, p = blockIdx.y;
    const bool isX = tg < mt128;
    const int t = isX ? tg : tg - mt128;
    const float* src = isX ? x : Xt;
    u16* dst = isX ? xbf : xtbf;
    const int nrows = isX ? B : N;
    if (isX) {
        int id = (p * mt128 + t) * 256 + tid;
        if (id < B) { best[id] = ~0ull; gminu[id] = ordf(1e30f); }
    }
    const int w = tid >> 6, L = tid & 63;
    const int col = L * 4;
    const int ks = col >> 5, j = col & 7, lhi = ((col >> 3) & 3) << 4;
    #pragma unroll
    for (int i = 0; i < 8; ++i) {
        int rloc = i * 4 + w;
        int grow = t * 128 + p * 32 + rloc;
        float4 v = make_float4(0.f, 0.f, 0.f, 0.f);
        if (grow < nrows) v = *(const float4*)(src + (size_t)grow * F_DIM + col);
        if (!isX) {
            float s = v.x * v.x + v.y * v.y + v.z * v.z + v.w * v.w;
            #pragma unroll
            for (int off = 32; off > 0; off >>= 1) s += __shfl_down(s, off, 64);
            if (L == 0) t2out[grow] = (grow < nrows) ? s : 1e30f;
        }
        u16* q = &tl[ks * 1024 + (rloc >> 4) * 512 + (((rloc & 15) | lhi)) * 8 + j];
        q[0] = f2bf(v.x); q[1] = f2bf(v.y); q[2] = f2bf(v.z); q[3] = f2bf(v.w);
    }
    __syncthreads();
    const uint4* s4 = (const uint4*)tl;
    uint4* d4 = (uint4*)(dst + (size_t)t * 32768);
    #pragma unroll
    for (int v = 0; v < 4; ++v) {
        int lin = v * 256 + tid;
        int ksc = lin >> 7, subl = (lin >> 6) & 1, lane = lin & 63;
        d4[(ksc * 8 + 2 * p + subl) * 64 + lane] = s4[lin];
    }
}

// ---------------- main: R15 = REVERT to R10 (best measured: knn 112 us, total 210.5 us) ----------------
// Session ledger on the knn floor (~11K cyc/pair-slot, all pipes <35%):
//   R5  traffic fixed (17 MB FETCH, spill-free)        -> 126 us
//   R6/R7 counted-vmcnt + sched_barrier pipeline       -> 143 us (REFUTED: compiler
//         schedules better; vmcnt polluted by stores)
//   R9  t2-before-STAGE (prefetch genuinely overlaps)  -> 113 us (CONFIRMED +13)
//   R10 one epilogue per 64-col pair (VALU 37->31%)    -> 112 us (work cut, time flat)
//   R13 4 independent 4-wave blocks (phase-lock test)  -> 124 us (REFUTED)
//   R14 5 blocks/CU (TLP test)                         -> 146 us (UNPACKABLE: 5x32 KB
//         > usable LDS; straggler tail. 32 KB blocks cap at 4/CU)
// Conclusion: dependent-chain latency floor for this structure family; escaping it
// needs a different structure class (producer/consumer wave specialization). R15
// locks in the best measured configuration = R10 byte-for-byte.
__global__ __launch_bounds__(512, 2) void knn_mfma(
    const u16* __restrict__ xbf, const u16* __restrict__ xtbf,
    const float* __restrict__ t2, u32* __restrict__ gminu,
    u32* __restrict__ wavecnt, u64* __restrict__ cands,
    int ntiles /*32-col tiles*/, int nch)
{
    __shared__ u16 sB[4][8192];   // 4 x 16 KB ring (32-col half-tiles, used in pairs)

    const int tid = threadIdx.x;
    const int L = tid & 63, w = tid >> 6;   // 8 waves
    const int lid = blockIdx.x;
    const int mbcnt = (int)(gridDim.x) / nch;
    int mb, chunk;
    if (nch == 64 && mbcnt == 8) {
        const int xg = lid & 7, slot = lid >> 3;
        chunk = xg * 8 + (slot >> 3);       // 8 chunks per XCD (round-robin or contiguous)
        mb = slot & 7;
    } else {
        mb = lid % mbcnt;                   // legacy linearization
        chunk = lid / mbcnt;
    }
    const int gwave = (mb * 64 + chunk) * 8 + w;
    const int t0 = (int)(((long long)chunk * ntiles) / nch);
    const int t1 = (int)(((long long)(chunk + 1) * ntiles) / nch);

    // nt is a 32-col half-tile: nt64 = nt>>1, half = nt&1
    #define TBASE_U32(nt) ((const AS1 u32*)xtbf + (size_t)((nt) >> 2) * 16384 \
                           + (size_t)(((nt) >> 1) & 1) * 1024 + (size_t)((nt) & 1) * 512)

    // ---- stage one 16 KB half-tile (async, 2 x 512 threads x 16 B) ----
    #define STAGE(buf, nt) do {                                                        \
        const AS1 u32* gp_ = TBASE_U32(nt);                                            \
        AS3 u32* lb_ = (AS3 u32*)&sB[buf][0];                                          \
        _Pragma("unroll")                                                              \
        for (int j = 0; j < 2; ++j) {                                                  \
            const int unit = j * 8 + w;                                                \
            __builtin_amdgcn_global_load_lds(                                          \
                gp_ + (size_t)(unit >> 1) * 2048 + (size_t)(unit & 1) * 256            \
                    + (size_t)L * 4,                                                   \
                lb_ + unit * 256, 16, 0, 0);                                           \
        }                                                                              \
    } while (0)

    STAGE(0, t0);
    if (t0 + 1 < t1) STAGE(1, t0 + 1);

    // ---- A fragments in registers: wave w owns rows mb*256 + w*32 .. +31 ----
    bf16x8 areg[16];
    {
        const int t128 = mb * 2 + (w >> 2);
        const u16* base = xbf + (size_t)t128 * 32768 + (size_t)(w & 3) * 1024 + (size_t)L * 8;
        #pragma unroll
        for (int ks = 0; ks < 8; ++ks)
            #pragma unroll
            for (int i = 0; i < 2; ++i)
                areg[ks * 2 + i] = *(const bf16x8*)(base + ks * 4096 + i * 512);
    }

    float rowmin_reg[2][4];
    #pragma unroll
    for (int i = 0; i < 2; ++i)
        #pragma unroll
        for (int r = 0; r < 4; ++r) rowmin_reg[i][r] = 1e30f;

    u32 wcount = 0;
    u64* const wreg = cands + (size_t)gwave * WCAP;

    __syncthreads();   // first pair staged

    for (int nt = t0; nt < t1; nt += 2) {
        const int cb = ((((nt - t0) >> 1) & 1) << 1);   // current buffer base (0 or 2)
        const bool has2 = (nt + 1 < t1);

        // t2 loads FIRST (R9): their wait must not drain the fresh prefetch.
        // Odd tail: t2v[2..3] = +inf -> those columns inert (never min / never captured).
        float t2v[4];
        #pragma unroll
        for (int c = 0; c < 2; ++c) t2v[c] = t2[nt * 32 + (L & 15) + c * 16];
        if (has2) {
            #pragma unroll
            for (int c = 2; c < 4; ++c) t2v[c] = t2[(nt + 1) * 32 + (L & 15) + (c - 2) * 16];
        } else {
            t2v[2] = 1e30f; t2v[3] = 1e30f;
        }

        // prefetch next pair into the other buffer pair (consumed after next barrier)
        if (nt + 2 < t1) STAGE(cb ^ 2, nt + 2);
        if (nt + 3 < t1) STAGE((cb ^ 2) + 1, nt + 3);

        // ---- MFMA over BOTH half-tiles into one acc[2][4] ----
        f32x4 acc[2][4];
        #pragma unroll
        for (int i = 0; i < 2; ++i)
            #pragma unroll
            for (int c = 0; c < 4; ++c)
                #pragma unroll
                for (int r = 0; r < 4; ++r) acc[i][c][r] = 0.f;

        #pragma unroll
        for (int ks = 0; ks < 8; ++ks) {
            bf16x8 bc[4];
            #pragma unroll
            for (int c = 0; c < 4; ++c)
                bc[c] = *(const bf16x8*)&sB[cb + (c >> 1)][ks * 1024 + (c & 1) * 512 + L * 8];
            #pragma unroll
            for (int i = 0; i < 2; ++i)
                #pragma unroll
                for (int c = 0; c < 4; ++c)
                    acc[i][c] = __builtin_amdgcn_mfma_f32_16x16x32_bf16(areg[ks * 2 + i], bc[c], acc[i][c], 0, 0, 0);
        }

        // ---- ONE epilogue per 64 cols ----
        const int colb = nt * 32 + (L & 15);   // col = colb + c*16, c in 0..3
        float r4[2][4];
        #pragma unroll
        for (int i = 0; i < 2; ++i) {
            #pragma unroll
            for (int r = 0; r < 4; ++r) r4[i][r] = 1e30f;
            #pragma unroll
            for (int c = 0; c < 4; ++c)
                #pragma unroll
                for (int r = 0; r < 4; ++r)
                    r4[i][r] = fminf(r4[i][r], fmaf(-2.f, acc[i][c][r], t2v[c]));
        }

        // threshold base (subset-min of the row's bf16 scores: safe with MARGIN >= 2E)
        float thb[2][4];
        if (nt == t0) {
            // seed: butterfly first-pair row-min FIRST so t0 capture doesn't flood
            #pragma unroll
            for (int i = 0; i < 2; ++i)
                #pragma unroll
                for (int r = 0; r < 4; ++r) rowmin_reg[i][r] = r4[i][r];
            #pragma unroll
            for (int st = 1; st <= 8; st <<= 1)
                #pragma unroll
                for (int i = 0; i < 2; ++i)
                    #pragma unroll
                    for (int r = 0; r < 4; ++r)
                        rowmin_reg[i][r] = fminf(rowmin_reg[i][r], __shfl_xor(rowmin_reg[i][r], st, 64));
            #pragma unroll
            for (int i = 0; i < 2; ++i)
                #pragma unroll
                for (int r = 0; r < 4; ++r) thb[i][r] = rowmin_reg[i][r];
        } else {
            #pragma unroll
            for (int i = 0; i < 2; ++i)
                #pragma unroll
                for (int r = 0; r < 4; ++r) thb[i][r] = fminf(rowmin_reg[i][r], r4[i][r]);
        }

        bool anyhit = false;
        #pragma unroll
        for (int i = 0; i < 2; ++i)
            #pragma unroll
            for (int r = 0; r < 4; ++r)
                anyhit = anyhit || (r4[i][r] < thb[i][r] + MARGIN);

        if (__any(anyhit)) {
            u32 cnt = 0;
            #pragma unroll
            for (int i = 0; i < 2; ++i)
                #pragma unroll
                for (int r = 0; r < 4; ++r) {
                    float th = thb[i][r] + MARGIN;
                    if (r4[i][r] < th) {
                        #pragma unroll
                        for (int c = 0; c < 4; ++c)
                            cnt += (fmaf(-2.f, acc[i][c][r], t2v[c]) < th) ? 1u : 0u;
                    }
                }
            u32 pre = cnt;
            #pragma unroll
            for (int d = 1; d < 64; d <<= 1) {
                u32 v = __shfl_up(pre, d, 64);
                if (L >= d) pre += v;
            }
            u32 total = __shfl(pre, 63, 64);
            u32 woff = wcount + pre - cnt;
            #pragma unroll
            for (int i = 0; i < 2; ++i)
                #pragma unroll
                for (int r = 0; r < 4; ++r) {
                    float th = thb[i][r] + MARGIN;
                    if (r4[i][r] < th) {
                        const int q = mb * 256 + w * 32 + i * 16 + (L >> 4) * 4 + r;
                        #pragma unroll
                        for (int c = 0; c < 4; ++c) {
                            float s = fmaf(-2.f, acc[i][c][r], t2v[c]);
                            if (s < th) {
                                if (woff < WCAP)
                                    wreg[woff] = ((u64)__float_as_uint(s) << 32)
                                               | (u64)(((u32)q << 16) | (u32)(colb + c * 16));
                                woff++;
                            }
                        }
                    }
                }
            wcount += total;
        }

        // fold per-lane; full 16-lane butterfly every 2nd pair (= every 4 half-tiles)
        #pragma unroll
        for (int i = 0; i < 2; ++i)
            #pragma unroll
            for (int r = 0; r < 4; ++r)
                rowmin_reg[i][r] = fminf(rowmin_reg[i][r], r4[i][r]);
        if (((nt - t0) & 2) == 2) {
            #pragma unroll
            for (int st = 1; st <= 8; st <<= 1)
                #pragma unroll
                for (int i = 0; i < 2; ++i)
                    #pragma unroll
                    for (int r = 0; r < 4; ++r)
                        rowmin_reg[i][r] = fminf(rowmin_reg[i][r], __shfl_xor(rowmin_reg[i][r], st, 64));
        }

        __syncthreads();   // drains pair prefetch + protects buffer reuse (1 barrier / 2 tiles)
    }

    // ---- final: exact chunk row-min -> global gmin atomics + candidate count ----
    #pragma unroll
    for (int st = 1; st <= 8; st <<= 1)
        #pragma unroll
        for (int i = 0; i < 2; ++i)
            #pragma unroll
            for (int r = 0; r < 4; ++r)
                rowmin_reg[i][r] = fminf(rowmin_reg[i][r], __shfl_xor(rowmin_reg[i][r], st, 64));
    if ((L & 15) == 0) {
        #pragma unroll
        for (int i = 0; i < 2; ++i)
            #pragma unroll
            for (int r = 0; r < 4; ++r) {
                int q = mb * 256 + w * 32 + i * 16 + (L >> 4) * 4 + r;
                atomicMin(&gminu[q], ordf(rowmin_reg[i][r]));
            }
    }
    if (L == 0) wavecnt[gwave] = (wcount < WCAP) ? wcount : WCAP;
    #undef STAGE
    #undef TBASE_U32
}

// ---------------- filtered exact fp32 rescore: ballot-compacted, wave-cooperative ----------------
__global__ void rescore(const float* __restrict__ x, const float* __restrict__ Xt,
                        const float* __restrict__ t2, const u32* __restrict__ gminu,
                        const u32* __restrict__ wavecnt, const u64* __restrict__ cands,
                        u64* __restrict__ best) {
    const int L = threadIdx.x & 63;
    const int gw = blockIdx.x * (blockDim.x >> 6) + (threadIdx.x >> 6);
    if (gw >= NWAVE_CAP) return;
    u32 cnt = wavecnt[gw];
    if (cnt > WCAP) cnt = WCAP;
    const u64* reg = cands + (size_t)gw * WCAP;
    for (u32 base = 0; base < cnt; base += 64) {
        u32 i = base + L;
        u64 rec = 0; bool pass = false;
        if (i < cnt) {
            rec = reg[i];                                   // coalesced 512 B
            float sb = __uint_as_float((u32)(rec >> 32));
            int q = (int)((rec >> 16) & 0xFFFFu);
            pass = sb < iordf(gminu[q]) + FMARGIN;
        }
        u64 bal = __ballot(pass);
        while (bal) {
            int j = __ffsll((unsigned long long)bal) - 1;
            bal &= bal - 1;
            u64 r2 = __shfl(rec, j, 64);
            int q = (int)((r2 >> 16) & 0xFFFFu);
            int n = (int)(r2 & 0xFFFFu);
            float4 a = *((const float4*)(x  + (size_t)q * F_DIM) + L);
            float4 b = *((const float4*)(Xt + (size_t)n * F_DIM) + L);
            float d = fmaf(a.x, b.x, fmaf(a.y, b.y, fmaf(a.z, b.z, a.w * b.w)));
            #pragma unroll
            for (int st = 32; st > 0; st >>= 1) d += __shfl_xor(d, st, 64);
            if (L == 0) {
                float s = fmaf(-2.f, d, t2[n]);
                u64 p = ((u64)ordf(s) << 32) | (u32)n;
                atomicMin(&best[q], p);
            }
        }
    }
}

// ---------------- gather Y[nearest] ----------------
__global__ void gather_kernel(const float* __restrict__ Y, const u64* __restrict__ best,
                              float* __restrict__ out, int B, int N) {
    int gid = blockIdx.x * blockDim.x + threadIdx.x;
    int total = B * O_DIM;
    if (gid >= total) return;
    int b = gid / O_DIM;
    int o = gid - b * O_DIM;
    u32 n = (u32)(best[b] & 0xFFFFFFFFull);
    if (n >= (u32)N) n = 0;   // defensive
    out[gid] = Y[(size_t)n * O_DIM + o];
}

// ================= fp32 fallback (proven Round-1 path, used if ws too small) =================
#define BM 128
#define BN 128
#define BK 16
#define NSPLIT 64
#define LDA (BM + 4)

__global__ __launch_bounds__(256) void knn_main_fp32(
    const float* __restrict__ Xq, const float* __restrict__ Xt,
    const float* __restrict__ t2, u64* __restrict__ best, int N)
{
    __shared__ float As[BK][LDA];
    __shared__ float Bs[BK][LDA];
    __shared__ u64 red[BM][17];

    const int tid = threadIdx.x;
    const int tx = tid & 15;
    const int ty = tid >> 4;
    const int m0 = blockIdx.y * BM;
    const int CHUNK = (N + NSPLIT - 1) / NSPLIT;
    const int n0c = blockIdx.x * CHUNK;
    const int n1c = min(N, n0c + CHUNK);

    u64 bestv[8];
    #pragma unroll
    for (int i = 0; i < 8; ++i) bestv[i] = ~0ull;

    const int srow = tid >> 2;
    const int scol4 = (tid & 3) * 4;

    for (int nt = n0c; nt < n1c; nt += BN) {
        float accl[8][8];
        #pragma unroll
        for (int i = 0; i < 8; ++i)
            #pragma unroll
            for (int j = 0; j < 8; ++j) accl[i][j] = 0.f;
        for (int k0 = 0; k0 < F_DIM; k0 += BK) {
            #pragma unroll
            for (int h = 0; h < 2; ++h) {
                int row = h * 64 + srow;
                float4 av = *(const float4*)(Xq + (size_t)(m0 + row) * F_DIM + k0 + scol4);
                As[scol4 + 0][row] = av.x; As[scol4 + 1][row] = av.y;
                As[scol4 + 2][row] = av.z; As[scol4 + 3][row] = av.w;
                int n = nt + row;
                float4 bv = make_float4(0.f, 0.f, 0.f, 0.f);
                if (n < n1c) bv = *(const float4*)(Xt + (size_t)n * F_DIM + k0 + scol4);
                Bs[scol4 + 0][row] = bv.x; Bs[scol4 + 1][row] = bv.y;
                Bs[scol4 + 2][row] = bv.z; Bs[scol4 + 3][row] = bv.w;
            }
            __syncthreads();
            #pragma unroll
            for (int k = 0; k < BK; ++k) {
                float4 a0 = *(const float4*)&As[k][ty * 4];
                float4 a1 = *(const float4*)&As[k][64 + ty * 4];
                float4 b0 = *(const float4*)&Bs[k][tx * 4];
                float4 b1 = *(const float4*)&Bs[k][64 + tx * 4];
                float am[8] = {a0.x, a0.y, a0.z, a0.w, a1.x, a1.y, a1.z, a1.w};
                float bn[8] = {b0.x, b0.y, b0.z, b0.w, b1.x, b1.y, b1.z, b1.w};
                #pragma unroll
                for (int i = 0; i < 8; ++i)
                    #pragma unroll
                    for (int j = 0; j < 8; ++j)
                        accl[i][j] = fmaf(am[i], bn[j], accl[i][j]);
            }
            __syncthreads();
        }
        #pragma unroll
        for (int j = 0; j < 8; ++j) {
            int nl = (j < 4) ? (tx * 4 + j) : (64 + tx * 4 + (j - 4));
            int n = nt + nl;
            if (n < n1c) {
                float t2v = t2[n];
                #pragma unroll
                for (int i = 0; i < 8; ++i) {
                    float score = fmaf(-2.f, accl[i][j], t2v);
                    u64 p = ((u64)ordf(score) << 32) | (u32)n;
                    bestv[i] = (p < bestv[i]) ? p : bestv[i];
                }
            }
        }
    }
    #pragma unroll
    for (int i = 0; i < 8; ++i) {
        int ml = (i < 4) ? (ty * 4 + i) : (64 + ty * 4 + (i - 4));
        red[ml][tx] = bestv[i];
    }
    __syncthreads();
    if (tid < BM) {
        u64 b = red[tid][0];
        #pragma unroll
        for (int t = 1; t < 16; ++t) { u64 v = red[tid][t]; b = (v < b) ? v : b; }
        atomicMin(&best[m0 + tid], b);
    }
}

// ================= launch =================
extern "C" void kernel_launch(void* const* d_in, const int* in_sizes, int n_in,
                              void* d_out, int out_size, void* d_ws, size_t ws_size,
                              hipStream_t stream) {
    const float* x  = (const float*)d_in[0];
    const float* Xt = (const float*)d_in[1];
    const float* Yt = (const float*)d_in[2];
    float* out = (float*)d_out;

    const int B = in_sizes[0] / F_DIM;        // 2048
    const int N = in_sizes[1] / F_DIM;        // 50000
    const int NT128 = (N + 127) / 128;        // 391
    const int Npad = NT128 * 128;             // 50048
    const int NT64 = NT128 * 2;               // 782
    const int NT32 = NT64 * 2;                // 1564
    const int MB = B / 256;                   // 8
    const int MT128 = B / 128;                // 16
    const int NCH = 64;                       // 8*64 = 512 blocks = 2/CU (512 thr each)

    char* wsp = (char*)d_ws;
    size_t off = 0;
    auto nxt = [&](size_t bytes) {
        char* p = wsp + off;
        off = (off + bytes + 255) & ~(size_t)255;
        return p;
    };
    float* t2       = (float*)nxt((size_t)Npad * 4);
    u64*   best     = (u64*)  nxt((size_t)B * 8);
    u32*   wavecnt  = (u32*)  nxt((size_t)NWAVE_CAP * 4);
    u32*   gminu    = (u32*)  nxt((size_t)B * 4);
    u64*   cands    = (u64*)  nxt((size_t)NWAVE_CAP * WCAP * 8);
    u16*   xbf      = (u16*)  nxt((size_t)B * F_DIM * 2);
    u16*   xtbf     = (u16*)  nxt((size_t)Npad * F_DIM * 2);
    size_t required = off;

    if (ws_size >= required && B % 256 == 0 && MB * NCH * 8 <= NWAVE_CAP) {
        // 4 launches: convert_dual(x+Xt, fused init+t2), knn_mfma(+gmin atomics), rescore, gather
        convert_dual<<<dim3(MT128 + NT128, 4), 256, 0, stream>>>(
            x, xbf, B, Xt, xtbf, t2, N, MT128, best, gminu);
        knn_mfma<<<dim3(MB * NCH), 512, 0, stream>>>(xbf, xtbf, t2, gminu, wavecnt, cands, NT32, NCH);
        rescore<<<NWAVE_CAP / 4, 256, 0, stream>>>(x, Xt, t2, gminu, wavecnt, cands, best);
    } else {
        init_kernel<<<(B + 255) / 256, 256, 0, stream>>>(best, (u32*)nullptr, B);
        t2_kernel<<<(N + 3) / 4, 256, 0, stream>>>(Xt, t2, N, N);
        dim3 grid(NSPLIT, B / BM);
        knn_main_fp32<<<grid, 256, 0, stream>>>(x, Xt, t2, best, N);
    }

    int total = B * O_DIM;
    gather_kernel<<<(total + 255) / 256, 256, 0, stream>>>(Yt, best, out, B, N);
}